// Round 9
// baseline (613.546 us; speedup 1.0000x reference)
//
#include <hip/hip_runtime.h>
#include <hip/hip_bf16.h>

#define N_ROWS 65536
#define DIM    512
#define KCLS   512
#define BUCKET 256     // padded per-class bucket (max cnt ~170 < 256)
#define GRID   768     // 3 blocks/CU x 256 CU; all co-resident (LDS 28KB -> 5/CU cap)

typedef __bf16 bf16x8 __attribute__((ext_vector_type(8)));
typedef float  f32x16 __attribute__((ext_vector_type(16)));

__device__ __forceinline__ float bf2f(ushort u) {
    union { unsigned int i; float f; } v; v.i = ((unsigned int)u) << 16; return v.f;
}

#define A_STRIDE 40
#define B_STRIDE 40

// LDS layout (28672 B), aliased across phases
#define SM_A      0        // ushort[64*40]   = 5120
#define SM_B      5120     // ushort[256*40]  = 20480
#define SM_MPART  25600    // float[4][64]
#define SM_SPART  26624    // float[4][64]
#define SM_LL     27648    // float[64]
#define SM_OWN    27904    // float[64]
#define SM_LBL    28160    // int[64]
#define SM_REP    28416    // int[64]

__global__ __launch_bounds__(256, 3) void mono_kernel(
    const float* __restrict__ emb, const int* __restrict__ labels,
    const float* __restrict__ wp, const float* __restrict__ bp,
    ushort* __restrict__ embb, ushort* __restrict__ order16,
    int* __restrict__ counts, float* __restrict__ sums,
    ushort* __restrict__ centb, float* __restrict__ loss_acc,
    int* __restrict__ bars, float* __restrict__ out)
{
    __shared__ __align__(16) char smem[28672];

    const int tid  = threadIdx.x;
    const int wave = tid >> 6;
    const int lane = tid & 63;
    const int bid  = blockIdx.x;

    // ---------------- grid barrier (device-scope, G16) ----------------
    auto grid_barrier = [&](int* bar) {
        __syncthreads();
        if (tid == 0) {
            __threadfence();                 // release: drain to coherent point
            atomicAdd(bar, 1);
            while (atomicAdd(bar, 0) < GRID) __builtin_amdgcn_s_sleep(1);
            __threadfence();                 // acquire: invalidate stale L1/L2
        }
        __syncthreads();
    };

    // ======== Phase 1: normalize -> bf16 embb + histogram + bucket scatter ==
    for (int c = bid; c < N_ROWS / 4; c += GRID) {
        const int row = c * 4 + wave;
        const float4* ep = (const float4*)(emb + (size_t)row * DIM + lane * 8);
        const float4 e0 = ep[0], e1 = ep[1];
        float ss = e0.x*e0.x + e0.y*e0.y + e0.z*e0.z + e0.w*e0.w
                 + e1.x*e1.x + e1.y*e1.y + e1.z*e1.z + e1.w*e1.w;
        #pragma unroll
        for (int off = 1; off < 64; off <<= 1)
            ss += __shfl_xor(ss, off, 64);
        const float rn = 1.0f / fmaxf(sqrtf(ss), 1e-12f);

        bf16x8 h;
        h[0] = (__bf16)(e0.x * rn); h[1] = (__bf16)(e0.y * rn);
        h[2] = (__bf16)(e0.z * rn); h[3] = (__bf16)(e0.w * rn);
        h[4] = (__bf16)(e1.x * rn); h[5] = (__bf16)(e1.y * rn);
        h[6] = (__bf16)(e1.z * rn); h[7] = (__bf16)(e1.w * rn);
        *(bf16x8*)(embb + (size_t)row * DIM + lane * 8) = h;

        if (lane == 0) {
            const int l   = labels[row];
            const int pos = atomicAdd(&counts[l], 1);
            order16[l * BUCKET + pos] = (ushort)row;
        }
    }
    grid_barrier(&bars[0]);

    // ======== Phase 3: per-class sums & bf16 centroids ======================
    if (bid < KCLS) {
        float* part = (float*)smem;          // [4][DIM]
        const int cls  = bid;
        const int cnt  = counts[cls];
        const int base = cls * BUCKET;
        const int d8   = lane * 8;

        float a[8] = {};
        float b2[8] = {};
        int j = wave;
        for (; j + 4 < cnt; j += 8) {
            const int r1 = order16[base + j];
            const int r2 = order16[base + j + 4];
            const uint4 u1 = *(const uint4*)(embb + (size_t)r1 * DIM + d8);
            const uint4 u2 = *(const uint4*)(embb + (size_t)r2 * DIM + d8);
            const ushort* s1 = (const ushort*)&u1;
            const ushort* s2 = (const ushort*)&u2;
            #pragma unroll
            for (int q = 0; q < 8; ++q) { a[q] += bf2f(s1[q]); b2[q] += bf2f(s2[q]); }
        }
        if (j < cnt) {
            const int r = order16[base + j];
            const uint4 u = *(const uint4*)(embb + (size_t)r * DIM + d8);
            const ushort* s1 = (const ushort*)&u;
            #pragma unroll
            for (int q = 0; q < 8; ++q) a[q] += bf2f(s1[q]);
        }
        #pragma unroll
        for (int q = 0; q < 8; ++q) part[wave * DIM + d8 + q] = a[q] + b2[q];
        __syncthreads();

        const int d0 = tid * 2;
        const float s0 = part[0*DIM+d0]   + part[1*DIM+d0]   + part[2*DIM+d0]   + part[3*DIM+d0];
        const float s1 = part[0*DIM+d0+1] + part[1*DIM+d0+1] + part[2*DIM+d0+1] + part[3*DIM+d0+1];
        *(float2*)(sums + (size_t)cls * DIM + d0) = make_float2(s0, s1);
        const float cinv = 1.0f / fmaxf((float)cnt, 1.0f);
        const __bf16 c0 = (__bf16)(s0 * cinv);
        const __bf16 c1 = (__bf16)(s1 * cinv);
        ushort2 cpk;
        cpk.x = *(const ushort*)&c0;
        cpk.y = *(const ushort*)&c1;
        *(ushort2*)(centb + (size_t)cls * DIM + d0) = cpk;
    }
    grid_barrier(&bars[1]);

    // ======== Phase 5: MFMA GEMM + own + logsumexp + loss ===================
    ushort* A_lds = (ushort*)(smem + SM_A);
    ushort* B_lds = (ushort*)(smem + SM_B);
    float*  m_part = (float*)(smem + SM_MPART);
    float*  s_part = (float*)(smem + SM_SPART);
    float*  ll_s   = (float*)(smem + SM_LL);
    float*  own_s  = (float*)(smem + SM_OWN);
    int*    lbl_s  = (int*)  (smem + SM_LBL);
    int*    rep_s  = (int*)  (smem + SM_REP);

    const int ln31 = lane & 31;
    const int half = lane >> 5;
    const int srow = tid >> 2;
    const int sch  = (tid & 3) * 8;
    const float wv = fmaxf(wp[0], 1e-6f);
    const float bv = bp[0];

    // tiles: block b -> tile b; blocks 512..767 also do tile b+256 (768..1023)
    #pragma unroll 1
    for (int rep = 0; rep < 2; ++rep) {
        if (rep == 1 && bid < 512) break;
        const int t  = (rep == 0) ? bid : bid + 256;
        const int r0 = t * 64;

        __syncthreads();                       // protect LDS reuse across tiles
        m_part[wave * 64 + lane] = -1e30f;
        s_part[wave * 64 + lane] = 0.f;

        // ---- Phase A: leave-one-out own logit per row ----
        for (int rr = wave; rr < 64; rr += 4) {
            const int row = r0 + rr;
            const int l   = labels[row];
            const uint4 ev = *(const uint4*)(embb + (size_t)row * DIM + lane * 8);
            const ushort* eu = (const ushort*)&ev;
            const float4* sp = (const float4*)(sums + (size_t)l * DIM + lane * 8);
            const float4 s0 = sp[0], s1 = sp[1];
            const float sv[8] = {s0.x, s0.y, s0.z, s0.w, s1.x, s1.y, s1.z, s1.w};
            float d1 = 0.f, d2 = 0.f;
            #pragma unroll
            for (int jj = 0; jj < 8; ++jj) {
                const float e  = bf2f(eu[jj]);
                const float df = sv[jj] - e;
                d1 += e * df;
                d2 += df * df;
            }
            #pragma unroll
            for (int off = 32; off > 0; off >>= 1) {
                d1 += __shfl_down(d1, off, 64);
                d2 += __shfl_down(d2, off, 64);
            }
            if (lane == 0) {
                own_s[rr] = d1 / fmaxf(sqrtf(d2), 1e-12f);
                lbl_s[rr] = l;
                rep_s[rr] = (counts[l] > 1) ? 1 : 0;
            }
        }
        __syncthreads();

        const ushort* aSrc = embb + (size_t)(r0 + srow) * DIM + sch;
        ushort* aDst = A_lds + srow * A_STRIDE + sch;
        ushort* bDst = B_lds + srow * B_STRIDE + sch;
        const ushort* Ard = A_lds + ln31 * A_STRIDE + half * 8;
        const ushort* Brd = B_lds + (wave * 64 + ln31) * B_STRIDE + half * 8;
        const int rot = (t * 7) & 15;

        #pragma unroll 1
        for (int ph = 0; ph < 2; ++ph) {
            const ushort* bBase = centb + (size_t)(ph * 256) * DIM;
            f32x16 acc[2][2] = {};

            #pragma unroll 1
            for (int ic = 0; ic < 16; ++ic) {
                const int kk = ((ic + rot) & 15) * 32;
                *(uint4*)aDst = *(const uint4*)(aSrc + kk);
                #pragma unroll
                for (int it = 0; it < 4; ++it)
                    *(uint4*)(bDst + it * 64 * B_STRIDE) =
                        *(const uint4*)(bBase + (size_t)(srow + it * 64) * DIM + sch + kk);
                __syncthreads();

                #pragma unroll
                for (int ks = 0; ks < 2; ++ks) {
                    const int ko = ks * 16;
                    const bf16x8 a0 = *(const bf16x8*)(Ard + ko);
                    const bf16x8 a1 = *(const bf16x8*)(Ard + 32 * A_STRIDE + ko);
                    const bf16x8 b0 = *(const bf16x8*)(Brd + ko);
                    const bf16x8 b1 = *(const bf16x8*)(Brd + 32 * B_STRIDE + ko);
                    acc[0][0] = __builtin_amdgcn_mfma_f32_32x32x16_bf16(a0, b0, acc[0][0], 0, 0, 0);
                    acc[0][1] = __builtin_amdgcn_mfma_f32_32x32x16_bf16(a0, b1, acc[0][1], 0, 0, 0);
                    acc[1][0] = __builtin_amdgcn_mfma_f32_32x32x16_bf16(a1, b0, acc[1][0], 0, 0, 0);
                    acc[1][1] = __builtin_amdgcn_mfma_f32_32x32x16_bf16(a1, b1, acc[1][1], 0, 0, 0);
                }
                __syncthreads();
            }

            // merge this phase's 256 cols into running (m,s)
            #pragma unroll
            for (int mt = 0; mt < 2; ++mt) {
                #pragma unroll
                for (int reg = 0; reg < 16; ++reg) {
                    const int row = mt * 32 + (reg & 3) + 8 * (reg >> 2) + 4 * half;
                    const int lbl = lbl_s[row];
                    float vals[2];
                    float mx = -1e30f;
                    #pragma unroll
                    for (int jn = 0; jn < 2; ++jn) {
                        const int col = ph * 256 + wave * 64 + jn * 32 + ln31;
                        float lg = wv * acc[mt][jn][reg] + bv;
                        if (col == lbl) {
                            if (rep_s[row]) lg = wv * own_s[row] + bv;
                            ll_s[row] = lg;
                        }
                        vals[jn] = lg;
                        mx = fmaxf(mx, lg);
                    }
                    #pragma unroll
                    for (int off = 1; off < 32; off <<= 1)
                        mx = fmaxf(mx, __shfl_xor(mx, off, 64));
                    float s = __expf(vals[0] - mx) + __expf(vals[1] - mx);
                    #pragma unroll
                    for (int off = 1; off < 32; off <<= 1)
                        s += __shfl_xor(s, off, 64);
                    if (ln31 == 0) {
                        const float mo = m_part[wave * 64 + row];
                        const float mn = fmaxf(mo, mx);
                        s_part[wave * 64 + row] = s_part[wave * 64 + row] * __expf(mo - mn)
                                                + s * __expf(mx - mn);
                        m_part[wave * 64 + row] = mn;
                    }
                }
            }
        }
        __syncthreads();

        if (tid < 64) {
            const int row = tid;
            float m0 = m_part[0*64+row], m1 = m_part[1*64+row];
            float m2 = m_part[2*64+row], m3 = m_part[3*64+row];
            float mt = fmaxf(fmaxf(m0, m1), fmaxf(m2, m3));
            float st = s_part[0*64+row] * __expf(m0 - mt)
                     + s_part[1*64+row] * __expf(m1 - mt)
                     + s_part[2*64+row] * __expf(m2 - mt)
                     + s_part[3*64+row] * __expf(m3 - mt);
            float loss = mt + __logf(st) - ll_s[row];
            #pragma unroll
            for (int off = 32; off > 0; off >>= 1)
                loss += __shfl_down(loss, off, 64);
            if (tid == 0) atomicAdd(loss_acc, loss);
        }
        __syncthreads();                       // m_part/s_part safe to re-init
    }

    // ======== finalize ======================================================
    grid_barrier(&bars[2]);
    if (bid == 0 && tid == 0) {
        const float tot = atomicAdd(loss_acc, 0.0f);
        out[0] = tot / (float)N_ROWS;
    }
}

extern "C" void kernel_launch(void* const* d_in, const int* in_sizes, int n_in,
                              void* d_out, int out_size, void* d_ws, size_t ws_size,
                              hipStream_t stream)
{
    const float* emb    = (const float*)d_in[0];
    const int*   labels = (const int*)d_in[1];
    const float* wp     = (const float*)d_in[2];
    const float* bp     = (const float*)d_in[3];
    float* out = (float*)d_out;

    char* ws = (char*)d_ws;
    ushort* embb    = (ushort*)(ws + 0);              // 64 MiB
    ushort* order16 = (ushort*)(ws + 67108864);       // 256 KiB
    float*  sums    = (float*) (ws + 67371008);       // 1 MiB
    ushort* centb   = (ushort*)(ws + 68419584);       // 512 KiB
    int*    counts  = (int*)   (ws + 68943872);       // 2048 B
    float*  loss_acc= (float*) (ws + 68945920);       // 4 B
    int*    bars    = (int*)   (ws + 68945924);       // 12 B

    // zero counts + loss_acc + bars in one memset (contiguous 2064 B)
    hipMemsetAsync(counts, 0, 2064, stream);

    mono_kernel<<<GRID, 256, 0, stream>>>(emb, labels, wp, bp, embb, order16,
                                          counts, sums, centb, loss_acc, bars, out);
}